// Round 3
// baseline (343.564 us; speedup 1.0000x reference)
//
#include <hip/hip_runtime.h>
#include <cmath>

#define BB 2
#define AA 5
#define CH 64
#define HH 128
#define WW 128
#define HW (HH*WW)
#define NIMG (BB*AA)

typedef __attribute__((ext_vector_type(8))) _Float16 half8;
typedef __attribute__((ext_vector_type(2))) _Float16 half2v;
typedef __attribute__((ext_vector_type(4))) float floatx4;
typedef unsigned int uint32;
typedef __attribute__((ext_vector_type(4))) uint32 uint4v;

__device__ inline half8 hzero() {
    half8 v;
#pragma unroll
    for (int e = 0; e < 8; ++e) v[e] = (_Float16)0.f;
    return v;
}

__device__ inline float fsigmoid(float x) {
    return __builtin_amdgcn_rcpf(1.f + __builtin_amdgcn_exp2f(-1.442695041f * x));
}
__device__ inline float ftanh(float x) {
    return 2.f * fsigmoid(2.f * x) - 1.f;
}

// ---------------------------------------------------------------------------
// feats fp32 planar [NIMG,64,H,W] -> NHWC f16 buffer channels 0..63
// ---------------------------------------------------------------------------
__global__ __launch_bounds__(256) void to_nhwc_kernel(
    const float* __restrict__ src, _Float16* __restrict__ dst)
{
    const int img = blockIdx.y;
    const int cg  = blockIdx.x & 7;
    const int pb  = blockIdx.x >> 3;
    const int p   = pb * 256 + threadIdx.x;
    const float* s = src + ((size_t)img * CH + cg * 8) * HW + p;
    half8 v;
#pragma unroll
    for (int e = 0; e < 8; ++e) v[e] = (_Float16)s[e * HW];
    *(half8*)(dst + ((size_t)img * HW + p) * 128 + cg * 8) = v;
}

// ---------------------------------------------------------------------------
// pack wx [192,128,3,3] fp32 -> f16 B-fragment layout:
// wp[cc][tap][gk][oc][e] : k = cc*32 + gk*8 + e, tap = ky*3+kx
// ---------------------------------------------------------------------------
__global__ __launch_bounds__(256) void pack_w_kernel(
    const float* __restrict__ wx, half8* __restrict__ wp)
{
    int idx = blockIdx.x * 256 + threadIdx.x;     // 4*9*4*192 = 27648
    if (idx >= 4 * 9 * 4 * 192) return;
    int oc = idx % 192; int r = idx / 192;
    int gk = r & 3; r >>= 2; int tap = r % 9; int cc = r / 9;
    int ky = tap / 3, kx = tap % 3;
    half8 v;
#pragma unroll
    for (int e = 0; e < 8; ++e)
        v[e] = (_Float16)wx[(((size_t)oc * 128 + cc * 32 + gk * 8 + e) * 3 + ky) * 3 + kx];
    wp[idx] = v;
}

// ---------------------------------------------------------------------------
// warp_mean v2 (unchanged): one block = 16x8 px tile x ALL 64 ch.
// ---------------------------------------------------------------------------
__global__ __launch_bounds__(256, 5) void warp_mean_kernel(
    const _Float16* __restrict__ nh,     // [NIMG, HW, 128]
    const float* __restrict__ trans,     // [B, A, A, 4, 4]
    _Float16* __restrict__ nhw)          // same buffer, writes ch 64..127
{
    __shared__ uint32 f_lds[32 * 9 * 18];   // 20736 B

    const int tile = blockIdx.x;
    const int tx0 = (tile & 7) * 16;
    const int ty0 = (tile >> 3) * 8;
    const int bi  = blockIdx.z;
    const int b   = bi / AA, i = bi % AA;
    const int tid = threadIdx.x;

    const int slc = tid & 7;
    const int ptb = tid >> 3;
    const int col = tid & 15;
    const int row = (tid >> 4) & 7;
    const int chh = tid >> 7;

    half2v acc[16];
#pragma unroll
    for (int c = 0; c < 16; ++c) acc[c] = (half2v)(_Float16)0.f;

    for (int j = 0; j < AA; ++j) {
        if (j == i) continue;
        const float* t = trans + (((size_t)b * AA + i) * AA + j) * 16;
        const float t00 = t[0], t01 = t[1], t03 = t[3];
        const float t10 = t[4], t11 = t[5], t13 = t[7];
        const float dxs = 2.f * t03;
        const float dys = -2.f * t13;
        const float sxf = floorf(dxs), syf = floorf(dys);
        const int sx = (int)sxf, sy = (int)syf;
        const float fx = dxs - sxf, fy = dys - syf;
        const _Float16* srcj = nh + (size_t)(b * AA + j) * HW * 128 + slc * 8;

        __syncthreads();
#pragma unroll
        for (int it = 0; it < 5; ++it) {
            const int pt = it * 32 + ptb;
            if (pt < 153) {
                const int prow = pt / 17;
                const int pcol = pt - prow * 17;
                const int qx = tx0 + sx + pcol;
                const int qy = ty0 + sy + prow;
                float e[8];
#pragma unroll
                for (int k = 0; k < 8; ++k) e[k] = 0.f;
                if (((unsigned)qx < (unsigned)WW) & ((unsigned)qy < (unsigned)HH)) {
                    const float xn = (2 * qx + 1) * (1.0f / WW) - 1.f;
                    const float yn = (2 * qy + 1) * (1.0f / HH) - 1.f;
                    const float px = 64.f * (t00 * xn + t01 * yn) + 63.5f;
                    const float py = 64.f * (t10 * xn + t11 * yn) + 63.5f;
                    const float x0f = floorf(px), y0f = floorf(py);
                    const int x0 = (int)x0f, y0 = (int)y0f;
                    const float wx1 = px - x0f, wx0 = 1.f - wx1;
                    const float wy1 = py - y0f, wy0 = 1.f - wy1;
                    const bool vx0 = (x0 >= 0) & (x0 < WW);
                    const bool vx1 = (x0 + 1 >= 0) & (x0 + 1 < WW);
                    const bool vy0 = (y0 >= 0) & (y0 < HH);
                    const bool vy1 = (y0 + 1 >= 0) & (y0 + 1 < HH);
                    const int cx0 = min(max(x0, 0), WW - 1);
                    const int cx1 = min(max(x0 + 1, 0), WW - 1);
                    const int cy0 = min(max(y0, 0), HH - 1);
                    const int cy1 = min(max(y0 + 1, 0), HH - 1);
                    const float w00 = (vx0 & vy0) ? wx0 * wy0 : 0.f;
                    const float w01 = (vx1 & vy0) ? wx1 * wy0 : 0.f;
                    const float w10 = (vx0 & vy1) ? wx0 * wy1 : 0.f;
                    const float w11 = (vx1 & vy1) ? wx1 * wy1 : 0.f;
                    const half8 A = *(const half8*)(srcj + ((size_t)cy0 * WW + cx0) * 128);
                    const half8 Bv = *(const half8*)(srcj + ((size_t)cy0 * WW + cx1) * 128);
                    const half8 Cv = *(const half8*)(srcj + ((size_t)cy1 * WW + cx0) * 128);
                    const half8 D = *(const half8*)(srcj + ((size_t)cy1 * WW + cx1) * 128);
#pragma unroll
                    for (int k = 0; k < 8; ++k)
                        e[k] = w00 * (float)A[k] + w01 * (float)Bv[k]
                             + w10 * (float)Cv[k] + w11 * (float)D[k];
                }
                const int lb = slc * 4 * 162 + prow * 18 + pcol;
#pragma unroll
                for (int k = 0; k < 4; ++k) {
                    half2v p;
                    p[0] = (_Float16)e[2 * k];
                    p[1] = (_Float16)e[2 * k + 1];
                    f_lds[lb + k * 162] = __builtin_bit_cast(uint32, p);
                }
            }
        }
        __syncthreads();

        const float wAf = (1.f - fx) * (1.f - fy);
        const float wBf = fx * (1.f - fy);
        const float wCf = (1.f - fx) * fy;
        const float wDf = fx * fy;
        half2v wA2 = (half2v)(_Float16)wAf;
        half2v wB2 = (half2v)(_Float16)wBf;
        half2v wC2 = (half2v)(_Float16)wCf;
        half2v wD2 = (half2v)(_Float16)wDf;
        const uint32* fp0 = f_lds + (chh * 16) * 162 + row * 18 + col;
#pragma unroll
        for (int c = 0; c < 16; ++c) {
            const uint32* fp = fp0 + c * 162;
            const half2v v00 = __builtin_bit_cast(half2v, fp[0]);
            const half2v v01 = __builtin_bit_cast(half2v, fp[1]);
            const half2v v10 = __builtin_bit_cast(half2v, fp[18]);
            const half2v v11 = __builtin_bit_cast(half2v, fp[19]);
            acc[c] += v00 * wA2 + v01 * wB2 + v10 * wC2 + v11 * wD2;
        }
    }

    const half2v q = (half2v)(_Float16)0.25f;   // 1/(A-1)
    uint32 os[16];
#pragma unroll
    for (int c = 0; c < 16; ++c) os[c] = __builtin_bit_cast(uint32, acc[c] * q);
    uint4v* dst = (uint4v*)(nhw + ((size_t)bi * HW + (ty0 + row) * WW + tx0 + col) * 128
                            + 64 + chh * 32);
#pragma unroll
    for (int k = 0; k < 4; ++k)
        dst[k] = (uint4v){os[4 * k], os[4 * k + 1], os[4 * k + 2], os[4 * k + 3]};
}

// ---------------------------------------------------------------------------
// MFMA implicit-GEMM 3x3 conv + fused GRU gating.
// v10: FORCED software pipeline. v7/v9 showed the compiler always collapses
// source-level prefetch to its min-reg schedule (VGPR=60, ds_read ->
// lgkmcnt(0) -> MFMA per step, ~280 cyc exposed LDS latency per step).
// Now: inline-asm ds_read_b128 with compile-time offsets (template-recursive
// K-loop), counted s_waitcnt lgkmcnt(4) (next step's 4 reads in flight
// across this step's 12 MFMAs), sched_barrier(0) after the waitcnt
// (rule #18: stops MFMA hoisting past an asm waitcnt). The K-loop's only
// lgkm producers are these 4 asm reads (weights use global_load -> vmcnt).
// ---------------------------------------------------------------------------
#define APL 110   // padded g-plane stride in half8 units

template <int S>
__device__ __forceinline__ void issue_a(uint32 abase, half8 (&dst)[4]) {
    constexpr int cc = S / 9, tap = S % 9, dy = tap / 3, dx = tap % 3;
    constexpr int base = ((cc * 4) * APL + dy * 18 + dx) * 16;
    asm volatile("ds_read_b128 %0, %1 offset:%c2"
                 : "=&v"(dst[0]) : "v"(abase), "i"(base + 0 * 288));
    asm volatile("ds_read_b128 %0, %1 offset:%c2"
                 : "=&v"(dst[1]) : "v"(abase), "i"(base + 1 * 288));
    asm volatile("ds_read_b128 %0, %1 offset:%c2"
                 : "=&v"(dst[2]) : "v"(abase), "i"(base + 2 * 288));
    asm volatile("ds_read_b128 %0, %1 offset:%c2"
                 : "=&v"(dst[3]) : "v"(abase), "i"(base + 3 * 288));
}

template <int S>
struct KLoop {
    static __device__ __forceinline__ void run(
        const half8* __restrict__ wbase, uint32 abase,
        half8 (&cur)[4], half8 (&nxt)[4],
        half8 (&bp0)[3], half8 (&bp1)[3], floatx4 (&acc)[4][3])
    {
        if constexpr (S + 1 < 36) issue_a<(S + 1 < 36) ? S + 1 : 0>(abase, nxt);
        asm volatile("s_waitcnt lgkmcnt(%c0)" :: "i"((S + 1 < 36) ? 4 : 0) : "memory");
        __builtin_amdgcn_sched_barrier(0);
        half8 bcur[3];
#pragma unroll
        for (int t = 0; t < 3; ++t) { bcur[t] = bp0[t]; bp0[t] = bp1[t]; }
        if constexpr (S + 2 < 36) {
            const half8* wsrc = wbase + (size_t)(S + 2) * 768;
#pragma unroll
            for (int t = 0; t < 3; ++t) bp1[t] = wsrc[t * 64];
        }
#pragma unroll
        for (int t = 0; t < 4; ++t)
#pragma unroll
            for (int u = 0; u < 3; ++u)
                acc[t][u] = __builtin_amdgcn_mfma_f32_16x16x32_f16(cur[t], bcur[u], acc[t][u], 0, 0, 0);
        KLoop<S + 1>::run(wbase, abase, nxt, cur, bp0, bp1, acc);
    }
};
template <>
struct KLoop<36> {
    static __device__ __forceinline__ void run(
        const half8* __restrict__, uint32, half8 (&)[4], half8 (&)[4],
        half8 (&)[3], half8 (&)[3], floatx4 (&)[4][3]) {}
};

__global__ __launch_bounds__(256, 3) void conv_gru_mfma(
    const _Float16* __restrict__ in,    // [NIMG, HW, 128]
    const half8* __restrict__ wp,       // packed weights [36][768]
    const float* __restrict__ bx,       // [192]
    const float* __restrict__ bh,       // [192]
    float* __restrict__ out_f32,        // [NIMG,64,H,W] or null
    _Float16* __restrict__ out_f16)     // [NIMG,HW,128] ch0..63 or null
{
    __shared__ half8 lds_in[16 * APL];   // 28160 B

    const int tid = threadIdx.x;
    const int img = blockIdx.z;
    const int x0 = (blockIdx.x & 7) * 16;       // 8 x-tiles
    const int y0 = (blockIdx.x >> 3) * 4;       // 32 y-tiles
    const int w   = tid >> 6;                   // wave -> c-range w*16..+15
    const int ln  = tid & 15;
    const int kq  = (tid & 63) >> 4;

    // ---- stage 6x18 halo x 128ch (only barrier in the kernel) ----
    const _Float16* inimg = in + (size_t)img * HW * 128;
    for (int f = tid; f < 1728; f += 256) {
        const int g = f / 108; const int r = f % 108;
        const int row = r / 18; const int col = r % 18;
        const int y = y0 + row - 1, x = x0 + col - 1;
        half8 v = hzero();
        if ((unsigned)x < (unsigned)WW && (unsigned)y < (unsigned)HH)
            v = *(const half8*)(inimg + ((size_t)y * WW + x) * 128 + g * 8);
        lds_in[g * APL + r] = v;
    }

    floatx4 acc[4][3];     // [y-row][gate]
#pragma unroll
    for (int s = 0; s < 4; ++s)
#pragma unroll
        for (int t = 0; t < 3; ++t)
#pragma unroll
            for (int r = 0; r < 4; ++r) acc[s][t][r] = 0.f;

    __syncthreads();

    // ---- forced-pipeline K-loop ----
    const half8* wbase = wp + kq * 192 + w * 16 + ln;
    half8 bp0[3], bp1[3];
#pragma unroll
    for (int t = 0; t < 3; ++t) bp0[t] = wbase[t * 64];
#pragma unroll
    for (int t = 0; t < 3; ++t) bp1[t] = wbase[768 + t * 64];

    // LDS byte address of this lane's a-frag base. Shared-aperture trick:
    // generic LDS pointer's low 32 bits are the LDS byte offset (aperture
    // is 4 GB aligned) — same pattern CK/HK use.
    const uint32 abase = (uint32)(size_t)(&lds_in[0]) + (uint32)((kq * APL + ln) * 16);

    half8 aA[4], aB[4];
    issue_a<0>(abase, aA);
    KLoop<0>::run(wbase, abase, aA, aB, bp0, bp1, acc);

    // epilogue: GRU gating. D layout: col(oc%16)=ln, row(x)=kq*4+reg.
    const int c = w * 16 + ln;                  // 0..63
    const float bxr = bx[c] + bh[c];
    const float bxz = bx[64 + c] + bh[64 + c];
    const float bxn = bx[128 + c];
    const float bnn = bh[128 + c];
#pragma unroll
    for (int s = 0; s < 4; ++s) {
        const int y = y0 + s;
#pragma unroll
        for (int reg = 0; reg < 4; ++reg) {
            const int x = x0 + kq * 4 + reg;
            const float xr = acc[s][0][reg] + bxr;
            const float xz = acc[s][1][reg] + bxz;
            const float xn = acc[s][2][reg] + bxn;
            const float rg = fsigmoid(xr);
            const float zg = fsigmoid(xz);
            const float n  = ftanh(xn + rg * bnn);
            const float h  = (1.f - zg) * n;
            if (out_f32)
                out_f32[((size_t)img * CH + c) * HW + y * WW + x] = h;
            else
                out_f16[((size_t)img * HW + y * WW + x) * 128 + c] = (_Float16)h;
        }
    }
}

// ---------------------------------------------------------------------------
extern "C" void kernel_launch(void* const* d_in, const int* in_sizes, int n_in,
                              void* d_out, int out_size, void* d_ws, size_t ws_size,
                              hipStream_t stream) {
    const float* feats = (const float*)d_in[0];
    const float* trans = (const float*)d_in[1];
    const float* wx    = (const float*)d_in[2];
    // d_in[3] = wh (unused: h0 = 0)
    const float* bx    = (const float*)d_in[4];
    const float* bh    = (const float*)d_in[5];
    float* out = (float*)d_out;

    char* ws = (char*)d_ws;
    half8*    wpack = (half8*)ws;                              // 442,368 B
    _Float16* B1 = (_Float16*)(ws + 442368);                   // 40 MB NHWC f16
    _Float16* B2 = (_Float16*)(ws + 442368 + (size_t)NIMG * HW * 128 * 2);

    pack_w_kernel<<<108, 256, 0, stream>>>(wx, wpack);
    to_nhwc_kernel<<<dim3(512, NIMG), 256, 0, stream>>>(feats, B1);

    dim3 wgrid(128, 1, NIMG);      // warp_mean: 16x8 px tiles
    dim3 cgrid(256, 1, NIMG);      // conv: 16x4 px tiles (8 x 32)

    // iteration 1
    warp_mean_kernel<<<wgrid, 256, 0, stream>>>(B1, trans, B1);
    conv_gru_mfma<<<cgrid, 256, 0, stream>>>(B1, wpack, bx, bh, nullptr, B2);
    // iteration 2
    warp_mean_kernel<<<wgrid, 256, 0, stream>>>(B2, trans, B2);
    conv_gru_mfma<<<cgrid, 256, 0, stream>>>(B2, wpack, bx, bh, out, nullptr);
}

// Round 4
// 328.731 us; speedup vs baseline: 1.0451x; 1.0451x over previous
//
#include <hip/hip_runtime.h>
#include <cmath>

#define BB 2
#define AA 5
#define CH 64
#define HH 128
#define WW 128
#define HW (HH*WW)
#define NIMG (BB*AA)

typedef __attribute__((ext_vector_type(8))) _Float16 half8;
typedef __attribute__((ext_vector_type(2))) _Float16 half2v;
typedef __attribute__((ext_vector_type(4))) float floatx4;
typedef unsigned int uint32;
typedef __attribute__((ext_vector_type(4))) uint32 uint4v;

__device__ inline half8 hzero() {
    half8 v;
#pragma unroll
    for (int e = 0; e < 8; ++e) v[e] = (_Float16)0.f;
    return v;
}

__device__ inline float fsigmoid(float x) {
    return __builtin_amdgcn_rcpf(1.f + __builtin_amdgcn_exp2f(-1.442695041f * x));
}
__device__ inline float ftanh(float x) {
    return 2.f * fsigmoid(2.f * x) - 1.f;
}

// ---------------------------------------------------------------------------
// feats fp32 planar [NIMG,64,H,W] -> NHWC f16 buffer channels 0..63
// ---------------------------------------------------------------------------
__global__ __launch_bounds__(256) void to_nhwc_kernel(
    const float* __restrict__ src, _Float16* __restrict__ dst)
{
    const int img = blockIdx.y;
    const int cg  = blockIdx.x & 7;
    const int pb  = blockIdx.x >> 3;
    const int p   = pb * 256 + threadIdx.x;
    const float* s = src + ((size_t)img * CH + cg * 8) * HW + p;
    half8 v;
#pragma unroll
    for (int e = 0; e < 8; ++e) v[e] = (_Float16)s[e * HW];
    *(half8*)(dst + ((size_t)img * HW + p) * 128 + cg * 8) = v;
}

// ---------------------------------------------------------------------------
// pack wx [192,128,3,3] fp32 -> f16 B-fragment layout:
// wp[cc][tap][gk][oc][e] : k = cc*32 + gk*8 + e, tap = ky*3+kx
// ---------------------------------------------------------------------------
__global__ __launch_bounds__(256) void pack_w_kernel(
    const float* __restrict__ wx, half8* __restrict__ wp)
{
    int idx = blockIdx.x * 256 + threadIdx.x;     // 4*9*4*192 = 27648
    if (idx >= 4 * 9 * 4 * 192) return;
    int oc = idx % 192; int r = idx / 192;
    int gk = r & 3; r >>= 2; int tap = r % 9; int cc = r / 9;
    int ky = tap / 3, kx = tap % 3;
    half8 v;
#pragma unroll
    for (int e = 0; e < 8; ++e)
        v[e] = (_Float16)wx[(((size_t)oc * 128 + cc * 32 + gk * 8 + e) * 3 + ky) * 3 + kx];
    wp[idx] = v;
}

// ---------------------------------------------------------------------------
// warp_mean v2 (unchanged): one block = 16x8 px tile x ALL 64 ch.
// ---------------------------------------------------------------------------
__global__ __launch_bounds__(256, 5) void warp_mean_kernel(
    const _Float16* __restrict__ nh,     // [NIMG, HW, 128]
    const float* __restrict__ trans,     // [B, A, A, 4, 4]
    _Float16* __restrict__ nhw)          // same buffer, writes ch 64..127
{
    __shared__ uint32 f_lds[32 * 9 * 18];   // 20736 B

    const int tile = blockIdx.x;
    const int tx0 = (tile & 7) * 16;
    const int ty0 = (tile >> 3) * 8;
    const int bi  = blockIdx.z;
    const int b   = bi / AA, i = bi % AA;
    const int tid = threadIdx.x;

    const int slc = tid & 7;
    const int ptb = tid >> 3;
    const int col = tid & 15;
    const int row = (tid >> 4) & 7;
    const int chh = tid >> 7;

    half2v acc[16];
#pragma unroll
    for (int c = 0; c < 16; ++c) acc[c] = (half2v)(_Float16)0.f;

    for (int j = 0; j < AA; ++j) {
        if (j == i) continue;
        const float* t = trans + (((size_t)b * AA + i) * AA + j) * 16;
        const float t00 = t[0], t01 = t[1], t03 = t[3];
        const float t10 = t[4], t11 = t[5], t13 = t[7];
        const float dxs = 2.f * t03;
        const float dys = -2.f * t13;
        const float sxf = floorf(dxs), syf = floorf(dys);
        const int sx = (int)sxf, sy = (int)syf;
        const float fx = dxs - sxf, fy = dys - syf;
        const _Float16* srcj = nh + (size_t)(b * AA + j) * HW * 128 + slc * 8;

        __syncthreads();
#pragma unroll
        for (int it = 0; it < 5; ++it) {
            const int pt = it * 32 + ptb;
            if (pt < 153) {
                const int prow = pt / 17;
                const int pcol = pt - prow * 17;
                const int qx = tx0 + sx + pcol;
                const int qy = ty0 + sy + prow;
                float e[8];
#pragma unroll
                for (int k = 0; k < 8; ++k) e[k] = 0.f;
                if (((unsigned)qx < (unsigned)WW) & ((unsigned)qy < (unsigned)HH)) {
                    const float xn = (2 * qx + 1) * (1.0f / WW) - 1.f;
                    const float yn = (2 * qy + 1) * (1.0f / HH) - 1.f;
                    const float px = 64.f * (t00 * xn + t01 * yn) + 63.5f;
                    const float py = 64.f * (t10 * xn + t11 * yn) + 63.5f;
                    const float x0f = floorf(px), y0f = floorf(py);
                    const int x0 = (int)x0f, y0 = (int)y0f;
                    const float wx1 = px - x0f, wx0 = 1.f - wx1;
                    const float wy1 = py - y0f, wy0 = 1.f - wy1;
                    const bool vx0 = (x0 >= 0) & (x0 < WW);
                    const bool vx1 = (x0 + 1 >= 0) & (x0 + 1 < WW);
                    const bool vy0 = (y0 >= 0) & (y0 < HH);
                    const bool vy1 = (y0 + 1 >= 0) & (y0 + 1 < HH);
                    const int cx0 = min(max(x0, 0), WW - 1);
                    const int cx1 = min(max(x0 + 1, 0), WW - 1);
                    const int cy0 = min(max(y0, 0), HH - 1);
                    const int cy1 = min(max(y0 + 1, 0), HH - 1);
                    const float w00 = (vx0 & vy0) ? wx0 * wy0 : 0.f;
                    const float w01 = (vx1 & vy0) ? wx1 * wy0 : 0.f;
                    const float w10 = (vx0 & vy1) ? wx0 * wy1 : 0.f;
                    const float w11 = (vx1 & vy1) ? wx1 * wy1 : 0.f;
                    const half8 A = *(const half8*)(srcj + ((size_t)cy0 * WW + cx0) * 128);
                    const half8 Bv = *(const half8*)(srcj + ((size_t)cy0 * WW + cx1) * 128);
                    const half8 Cv = *(const half8*)(srcj + ((size_t)cy1 * WW + cx0) * 128);
                    const half8 D = *(const half8*)(srcj + ((size_t)cy1 * WW + cx1) * 128);
#pragma unroll
                    for (int k = 0; k < 8; ++k)
                        e[k] = w00 * (float)A[k] + w01 * (float)Bv[k]
                             + w10 * (float)Cv[k] + w11 * (float)D[k];
                }
                const int lb = slc * 4 * 162 + prow * 18 + pcol;
#pragma unroll
                for (int k = 0; k < 4; ++k) {
                    half2v p;
                    p[0] = (_Float16)e[2 * k];
                    p[1] = (_Float16)e[2 * k + 1];
                    f_lds[lb + k * 162] = __builtin_bit_cast(uint32, p);
                }
            }
        }
        __syncthreads();

        const float wAf = (1.f - fx) * (1.f - fy);
        const float wBf = fx * (1.f - fy);
        const float wCf = (1.f - fx) * fy;
        const float wDf = fx * fy;
        half2v wA2 = (half2v)(_Float16)wAf;
        half2v wB2 = (half2v)(_Float16)wBf;
        half2v wC2 = (half2v)(_Float16)wCf;
        half2v wD2 = (half2v)(_Float16)wDf;
        const uint32* fp0 = f_lds + (chh * 16) * 162 + row * 18 + col;
#pragma unroll
        for (int c = 0; c < 16; ++c) {
            const uint32* fp = fp0 + c * 162;
            const half2v v00 = __builtin_bit_cast(half2v, fp[0]);
            const half2v v01 = __builtin_bit_cast(half2v, fp[1]);
            const half2v v10 = __builtin_bit_cast(half2v, fp[18]);
            const half2v v11 = __builtin_bit_cast(half2v, fp[19]);
            acc[c] += v00 * wA2 + v01 * wB2 + v10 * wC2 + v11 * wD2;
        }
    }

    const half2v q = (half2v)(_Float16)0.25f;   // 1/(A-1)
    uint32 os[16];
#pragma unroll
    for (int c = 0; c < 16; ++c) os[c] = __builtin_bit_cast(uint32, acc[c] * q);
    uint4v* dst = (uint4v*)(nhw + ((size_t)bi * HW + (ty0 + row) * WW + tx0 + col) * 128
                            + 64 + chh * 32);
#pragma unroll
    for (int k = 0; k < 4; ++k)
        dst[k] = (uint4v){os[4 * k], os[4 * k + 1], os[4 * k + 2], os[4 * k + 3]};
}

// ---------------------------------------------------------------------------
// MFMA implicit-GEMM 3x3 conv + fused GRU gating.
// v11: 512-thread blocks, 16x8 px tile, 8 waves = (y-half, oc-group).
// Per-wave inner loop is EXACTLY v7's verified code (acc[4][3], plain
// depth-2 b prefetch — v10's forced pipeline reverted: proven null).
// Why: v7's stall is correlated starvation (3 phase-locked waves/SIMD,
// 41% per-wave MFMA duty -> 63% pipe idle) + per-block 442 KB weight
// panel from L2 (84K cyc/CU = MFMA time; needs concurrency to overlap).
// This shape: weight traffic/CU halves, grid 1280 = exactly 5 blocks/CU
// (no tail), 2 blocks x 8 waves = 16 waves/CU from 2 independent blocks.
// ---------------------------------------------------------------------------
#define APL2 180   // g-plane stride in half8 units (10*18)

__global__ __launch_bounds__(512, 4) void conv_gru_mfma(
    const _Float16* __restrict__ in,    // [NIMG, HW, 128]
    const half8* __restrict__ wp,       // packed weights [36][768]
    const float* __restrict__ bx,       // [192]
    const float* __restrict__ bh,       // [192]
    float* __restrict__ out_f32,        // [NIMG,64,H,W] or null
    _Float16* __restrict__ out_f16)     // [NIMG,HW,128] ch0..63 or null
{
    __shared__ half8 lds_in[16 * APL2];   // 46080 B

    const int tid = threadIdx.x;
    const int img = blockIdx.z;
    const int x0 = (blockIdx.x & 7) * 16;       // 8 x-tiles
    const int y0 = (blockIdx.x >> 3) * 8;       // 16 y-tiles
    const int w   = tid >> 6;                   // wave 0..7
    const int wo  = w & 3;                      // oc-group: c-range wo*16..+15
    const int wh  = w >> 2;                     // y-half 0/1
    const int ln  = tid & 15;
    const int kq  = (tid & 63) >> 4;

    // ---- stage 10x18 halo x 128ch (only barrier in the kernel) ----
    const _Float16* inimg = in + (size_t)img * HW * 128;
    for (int f = tid; f < 2880; f += 512) {
        const int g = f / 180; const int r = f % 180;
        const int row = r / 18; const int col = r % 18;
        const int y = y0 + row - 1, x = x0 + col - 1;
        half8 v = hzero();
        if ((unsigned)x < (unsigned)WW && (unsigned)y < (unsigned)HH)
            v = *(const half8*)(inimg + ((size_t)y * WW + x) * 128 + g * 8);
        lds_in[f] = v;
    }

    floatx4 acc[4][3];     // [y-row][gate]
#pragma unroll
    for (int s = 0; s < 4; ++s)
#pragma unroll
        for (int t = 0; t < 3; ++t)
#pragma unroll
            for (int r = 0; r < 4; ++r) acc[s][t][r] = 0.f;

    __syncthreads();

    // ---- barrier-free K-loop, depth-2 b prefetch (v7-verified) ----
    const half8* wbase = wp + kq * 192 + wo * 16 + ln;
    half8 bp0[3], bp1[3];
#pragma unroll
    for (int t = 0; t < 3; ++t) bp0[t] = wbase[t * 64];
#pragma unroll
    for (int t = 0; t < 3; ++t) bp1[t] = wbase[768 + t * 64];

#pragma unroll
    for (int s = 0; s < 36; ++s) {
        const int cc = s / 9, tap = s - cc * 9;
        const int dy = tap / 3, dx = tap - dy * 3;
        half8 bcur[3];
#pragma unroll
        for (int t = 0; t < 3; ++t) { bcur[t] = bp0[t]; bp0[t] = bp1[t]; }
        if (s + 2 < 36) {
            const half8* wsrc = wbase + (size_t)(s + 2) * 768;
#pragma unroll
            for (int t = 0; t < 3; ++t) bp1[t] = wsrc[t * 64];
        }
        half8 a[4];
#pragma unroll
        for (int t = 0; t < 4; ++t)
            a[t] = lds_in[(cc * 4 + kq) * APL2 + (wh * 4 + t + dy) * 18 + ln + dx];
#pragma unroll
        for (int t = 0; t < 4; ++t)
#pragma unroll
            for (int u = 0; u < 3; ++u)
                acc[t][u] = __builtin_amdgcn_mfma_f32_16x16x32_f16(a[t], bcur[u], acc[t][u], 0, 0, 0);
    }

    // epilogue: GRU gating. D layout: col(oc%16)=ln, row(x)=kq*4+reg.
    const int c = wo * 16 + ln;                 // 0..63
    const float bxr = bx[c] + bh[c];
    const float bxz = bx[64 + c] + bh[64 + c];
    const float bxn = bx[128 + c];
    const float bnn = bh[128 + c];
#pragma unroll
    for (int s = 0; s < 4; ++s) {
        const int y = y0 + wh * 4 + s;
#pragma unroll
        for (int reg = 0; reg < 4; ++reg) {
            const int x = x0 + kq * 4 + reg;
            const float xr = acc[s][0][reg] + bxr;
            const float xz = acc[s][1][reg] + bxz;
            const float xn = acc[s][2][reg] + bxn;
            const float rg = fsigmoid(xr);
            const float zg = fsigmoid(xz);
            const float n  = ftanh(xn + rg * bnn);
            const float h  = (1.f - zg) * n;
            if (out_f32)
                out_f32[((size_t)img * CH + c) * HW + y * WW + x] = h;
            else
                out_f16[((size_t)img * HW + y * WW + x) * 128 + c] = (_Float16)h;
        }
    }
}

// ---------------------------------------------------------------------------
extern "C" void kernel_launch(void* const* d_in, const int* in_sizes, int n_in,
                              void* d_out, int out_size, void* d_ws, size_t ws_size,
                              hipStream_t stream) {
    const float* feats = (const float*)d_in[0];
    const float* trans = (const float*)d_in[1];
    const float* wx    = (const float*)d_in[2];
    // d_in[3] = wh (unused: h0 = 0)
    const float* bx    = (const float*)d_in[4];
    const float* bh    = (const float*)d_in[5];
    float* out = (float*)d_out;

    char* ws = (char*)d_ws;
    half8*    wpack = (half8*)ws;                              // 442,368 B
    _Float16* B1 = (_Float16*)(ws + 442368);                   // 40 MB NHWC f16
    _Float16* B2 = (_Float16*)(ws + 442368 + (size_t)NIMG * HW * 128 * 2);

    pack_w_kernel<<<108, 256, 0, stream>>>(wx, wpack);
    to_nhwc_kernel<<<dim3(512, NIMG), 256, 0, stream>>>(feats, B1);

    dim3 wgrid(128, 1, NIMG);      // warp_mean: 16x8 px tiles
    dim3 cgrid(128, 1, NIMG);      // conv: 16x8 px tiles, 512 threads

    // iteration 1
    warp_mean_kernel<<<wgrid, 256, 0, stream>>>(B1, trans, B1);
    conv_gru_mfma<<<cgrid, 512, 0, stream>>>(B1, wpack, bx, bh, nullptr, B2);
    // iteration 2
    warp_mean_kernel<<<wgrid, 256, 0, stream>>>(B2, trans, B2);
    conv_gru_mfma<<<cgrid, 512, 0, stream>>>(B2, wpack, bx, bh, out, nullptr);
}

// Round 5
// 312.456 us; speedup vs baseline: 1.0996x; 1.0521x over previous
//
#include <hip/hip_runtime.h>
#include <cmath>

#define BB 2
#define AA 5
#define CH 64
#define HH 128
#define WW 128
#define HW (HH*WW)
#define NIMG (BB*AA)

typedef __attribute__((ext_vector_type(8))) _Float16 half8;
typedef __attribute__((ext_vector_type(4))) float floatx4;
typedef unsigned int uint32;

__device__ inline half8 hzero() {
    half8 v;
#pragma unroll
    for (int e = 0; e < 8; ++e) v[e] = (_Float16)0.f;
    return v;
}

__device__ inline float fsigmoid(float x) {
    return __builtin_amdgcn_rcpf(1.f + __builtin_amdgcn_exp2f(-1.442695041f * x));
}
__device__ inline float ftanh(float x) {
    return 2.f * fsigmoid(2.f * x) - 1.f;
}

// ---------------------------------------------------------------------------
// feats fp32 planar [NIMG,64,H,W] -> NHWC f16 buffer [NIMG,HW,64]
// ---------------------------------------------------------------------------
__global__ __launch_bounds__(256) void to_nhwc_kernel(
    const float* __restrict__ src, _Float16* __restrict__ dst)
{
    const int img = blockIdx.y;
    const int cg  = blockIdx.x & 7;
    const int pb  = blockIdx.x >> 3;
    const int p   = pb * 256 + threadIdx.x;
    const float* s = src + ((size_t)img * CH + cg * 8) * HW + p;
    half8 v;
#pragma unroll
    for (int e = 0; e < 8; ++e) v[e] = (_Float16)s[e * HW];
    *(half8*)(dst + ((size_t)img * HW + p) * 64 + cg * 8) = v;
}

// ---------------------------------------------------------------------------
// pack wx [192,128,3,3] fp32 -> f16 B-fragment layout:
// wp[cc][tap][gk][oc][e] : k = cc*32 + gk*8 + e, tap = ky*3+kx
// (k channel order: 0..63 = feats, 64..127 = mean — unchanged)
// ---------------------------------------------------------------------------
__global__ __launch_bounds__(256) void pack_w_kernel(
    const float* __restrict__ wx, half8* __restrict__ wp)
{
    int idx = blockIdx.x * 256 + threadIdx.x;     // 4*9*4*192 = 27648
    if (idx >= 4 * 9 * 4 * 192) return;
    int oc = idx % 192; int r = idx / 192;
    int gk = r & 3; r >>= 2; int tap = r % 9; int cc = r / 9;
    int ky = tap / 3, kx = tap % 3;
    half8 v;
#pragma unroll
    for (int e = 0; e < 8; ++e)
        v[e] = (_Float16)wx[(((size_t)oc * 128 + cc * 32 + gk * 8 + e) * 3 + ky) * 3 + kx];
    wp[idx] = v;
}

// ---------------------------------------------------------------------------
// v12: FUSED warp_mean + conv + GRU.
// One block = 16x8 output tile, 512 threads.
// Phase 0: direct halo ch0..63 (18x10) -> LDS planes 0..7.
// Phase 1: warp-mean for the SAME 18x10 halo (gather grid 19x11 per j,
//          verified warp_mean math, tile origin shifted by (-1,-1)),
//          accumulated in registers over j, written to LDS planes 8..15.
//          Out-of-image halo px forced to zero (matches old bounds-checked
//          read of the mean buffer).
// Phase 2: v11's verified barrier-free MFMA K-loop + GRU epilogue.
// Rationale: conv is pinned at ~863 TF (44% of f16 ceiling) with VALU/VMEM
// mostly idle; warp_mean is VALU/VMEM work. Fusion hides gather in conv's
// idle pipes across 2 resident blocks/CU, removes 2 launches and the
// 20 MB mean round-trip; NHWC buffers shrink to 64-ch records.
// ---------------------------------------------------------------------------
#define APL2 180   // g-plane stride in half8 units (10*18)

__global__ __launch_bounds__(512, 4) void fused_warp_conv(
    const _Float16* __restrict__ in,    // [NIMG, HW, 64] prev feats (f16)
    const float* __restrict__ trans,    // [B, A, A, 4, 4]
    const half8* __restrict__ wp,       // packed weights [36][768]
    const float* __restrict__ bx,       // [192]
    const float* __restrict__ bh,       // [192]
    float* __restrict__ out_f32,        // [NIMG,64,H,W] or null
    _Float16* __restrict__ out_f16)     // [NIMG,HW,64] or null
{
    __shared__ half8 lds_in[16 * APL2];   // 46080 B: 16 ch-octet planes x 10x18
    __shared__ half8 f_lds[209 * 8];      // 26752 B: 19x11 gather pts x 8 octets

    const int tid = threadIdx.x;
    const int bi  = blockIdx.z;
    const int b   = bi / AA, i = bi % AA;
    const int x0 = (blockIdx.x & 7) * 16;       // 8 x-tiles
    const int y0 = (blockIdx.x >> 3) * 8;       // 16 y-tiles

    // conv roles
    const int w   = tid >> 6;                   // wave 0..7
    const int wo  = w & 3;                      // oc-group
    const int wh  = w >> 2;                     // y-half
    const int ln  = tid & 15;
    const int kq  = (tid & 63) >> 4;
    // gather roles
    const int slc = tid & 7;                    // ch octet
    const int ptb = tid >> 3;                   // 0..63 point slot

    // ---- phase 0: direct halo ch0..63 -> planes 0..7 ----
    const _Float16* inimg = in + (size_t)bi * HW * 64;
    for (int f = tid; f < 1440; f += 512) {
        const int g = f / 180; const int r = f % 180;
        const int row = r / 18; const int col = r % 18;
        const int y = y0 + row - 1, x = x0 + col - 1;
        half8 v = hzero();
        if ((unsigned)x < (unsigned)WW && (unsigned)y < (unsigned)HH)
            v = *(const half8*)(inimg + ((size_t)y * WW + x) * 64 + g * 8);
        lds_in[g * APL2 + r] = v;
    }

    // ---- phase 1: warp-mean over j != i for the 18x10 halo ----
    half8 macc[3];
#pragma unroll
    for (int k2 = 0; k2 < 3; ++k2) macc[k2] = hzero();

    for (int j = 0; j < AA; ++j) {
        if (j == i) continue;
        const float* t = trans + (((size_t)b * AA + i) * AA + j) * 16;
        const float t00 = t[0], t01 = t[1], t03 = t[3];
        const float t10 = t[4], t11 = t[5], t13 = t[7];
        const float dxs = 2.f * t03;
        const float dys = -2.f * t13;
        const float sxf = floorf(dxs), syf = floorf(dys);
        const int sx = (int)sxf, sy = (int)syf;
        const float fx = dxs - sxf, fy = dys - syf;
        const _Float16* srcj = in + (size_t)(b * AA + j) * HW * 64 + slc * 8;

        __syncthreads();   // f_lds free of previous j's readers
#pragma unroll
        for (int it = 0; it < 4; ++it) {
            const int pt = it * 64 + ptb;
            if (pt < 209) {
                const int prow = pt / 19;
                const int pcol = pt - prow * 19;
                const int qx = x0 - 1 + sx + pcol;
                const int qy = y0 - 1 + sy + prow;
                float e[8];
#pragma unroll
                for (int k = 0; k < 8; ++k) e[k] = 0.f;
                if (((unsigned)qx < (unsigned)WW) & ((unsigned)qy < (unsigned)HH)) {
                    const float xn = (2 * qx + 1) * (1.0f / WW) - 1.f;
                    const float yn = (2 * qy + 1) * (1.0f / HH) - 1.f;
                    const float px = 64.f * (t00 * xn + t01 * yn) + 63.5f;
                    const float py = 64.f * (t10 * xn + t11 * yn) + 63.5f;
                    const float x0f = floorf(px), y0f = floorf(py);
                    const int ix0 = (int)x0f, iy0 = (int)y0f;
                    const float wx1 = px - x0f, wx0 = 1.f - wx1;
                    const float wy1 = py - y0f, wy0 = 1.f - wy1;
                    const bool vx0 = (ix0 >= 0) & (ix0 < WW);
                    const bool vx1 = (ix0 + 1 >= 0) & (ix0 + 1 < WW);
                    const bool vy0 = (iy0 >= 0) & (iy0 < HH);
                    const bool vy1 = (iy0 + 1 >= 0) & (iy0 + 1 < HH);
                    const int cx0 = min(max(ix0, 0), WW - 1);
                    const int cx1 = min(max(ix0 + 1, 0), WW - 1);
                    const int cy0 = min(max(iy0, 0), HH - 1);
                    const int cy1 = min(max(iy0 + 1, 0), HH - 1);
                    const float w00 = (vx0 & vy0) ? wx0 * wy0 : 0.f;
                    const float w01 = (vx1 & vy0) ? wx1 * wy0 : 0.f;
                    const float w10 = (vx0 & vy1) ? wx0 * wy1 : 0.f;
                    const float w11 = (vx1 & vy1) ? wx1 * wy1 : 0.f;
                    const half8 A  = *(const half8*)(srcj + ((size_t)cy0 * WW + cx0) * 64);
                    const half8 Bv = *(const half8*)(srcj + ((size_t)cy0 * WW + cx1) * 64);
                    const half8 Cv = *(const half8*)(srcj + ((size_t)cy1 * WW + cx0) * 64);
                    const half8 D  = *(const half8*)(srcj + ((size_t)cy1 * WW + cx1) * 64);
#pragma unroll
                    for (int k = 0; k < 8; ++k)
                        e[k] = w00 * (float)A[k] + w01 * (float)Bv[k]
                             + w10 * (float)Cv[k] + w11 * (float)D[k];
                }
                half8 p;
#pragma unroll
                for (int k = 0; k < 8; ++k) p[k] = (_Float16)e[k];
                f_lds[pt * 8 + slc] = p;
            }
        }
        __syncthreads();   // staging visible

        const half8 wA8 = (half8)(_Float16)((1.f - fx) * (1.f - fy));
        const half8 wB8 = (half8)(_Float16)(fx * (1.f - fy));
        const half8 wC8 = (half8)(_Float16)((1.f - fx) * fy);
        const half8 wD8 = (half8)(_Float16)(fx * fy);
#pragma unroll
        for (int k2 = 0; k2 < 3; ++k2) {
            const int item = tid + 512 * k2;
            if (item < 1440) {
                const int px = item >> 3, g = item & 7;
                const int row = px / 18, col = px - row * 18;
                const half8* fp = &f_lds[(row * 19 + col) * 8 + g];
                macc[k2] += fp[0] * wA8 + fp[8] * wB8 + fp[152] * wC8 + fp[160] * wD8;
            }
        }
    }

    // mean -> planes 8..15 (zero outside image, matching old bounds check)
    {
        const half8 q8 = (half8)(_Float16)0.25f;   // 1/(A-1)
#pragma unroll
        for (int k2 = 0; k2 < 3; ++k2) {
            const int item = tid + 512 * k2;
            if (item < 1440) {
                const int px = item >> 3, g = item & 7;
                const int row = px / 18, col = px - row * 18;
                const int y = y0 + row - 1, x = x0 + col - 1;
                half8 v = hzero();
                if ((unsigned)x < (unsigned)WW && (unsigned)y < (unsigned)HH)
                    v = macc[k2] * q8;
                lds_in[(8 + g) * APL2 + row * 18 + col] = v;
            }
        }
    }

    floatx4 acc[4][3];     // [y-row][gate]
#pragma unroll
    for (int s = 0; s < 4; ++s)
#pragma unroll
        for (int t = 0; t < 3; ++t)
#pragma unroll
            for (int r = 0; r < 4; ++r) acc[s][t][r] = 0.f;

    __syncthreads();

    // ---- phase 2: v11's verified barrier-free K-loop, depth-2 b prefetch ----
    const half8* wbase = wp + kq * 192 + wo * 16 + ln;
    half8 bp0[3], bp1[3];
#pragma unroll
    for (int t = 0; t < 3; ++t) bp0[t] = wbase[t * 64];
#pragma unroll
    for (int t = 0; t < 3; ++t) bp1[t] = wbase[768 + t * 64];

#pragma unroll
    for (int s = 0; s < 36; ++s) {
        const int cc = s / 9, tap = s - cc * 9;
        const int dy = tap / 3, dx = tap - dy * 3;
        half8 bcur[3];
#pragma unroll
        for (int t = 0; t < 3; ++t) { bcur[t] = bp0[t]; bp0[t] = bp1[t]; }
        if (s + 2 < 36) {
            const half8* wsrc = wbase + (size_t)(s + 2) * 768;
#pragma unroll
            for (int t = 0; t < 3; ++t) bp1[t] = wsrc[t * 64];
        }
        half8 a[4];
#pragma unroll
        for (int t = 0; t < 4; ++t)
            a[t] = lds_in[(cc * 4 + kq) * APL2 + (wh * 4 + t + dy) * 18 + ln + dx];
#pragma unroll
        for (int t = 0; t < 4; ++t)
#pragma unroll
            for (int u = 0; u < 3; ++u)
                acc[t][u] = __builtin_amdgcn_mfma_f32_16x16x32_f16(a[t], bcur[u], acc[t][u], 0, 0, 0);
    }

    // epilogue: GRU gating. D layout: col(oc%16)=ln, row(x)=kq*4+reg.
    const int c = wo * 16 + ln;                 // 0..63
    const float bxr = bx[c] + bh[c];
    const float bxz = bx[64 + c] + bh[64 + c];
    const float bxn = bx[128 + c];
    const float bnn = bh[128 + c];
#pragma unroll
    for (int s = 0; s < 4; ++s) {
        const int y = y0 + wh * 4 + s;
#pragma unroll
        for (int reg = 0; reg < 4; ++reg) {
            const int x = x0 + kq * 4 + reg;
            const float xr = acc[s][0][reg] + bxr;
            const float xz = acc[s][1][reg] + bxz;
            const float xn = acc[s][2][reg] + bxn;
            const float rg = fsigmoid(xr);
            const float zg = fsigmoid(xz);
            const float n  = ftanh(xn + rg * bnn);
            const float h  = (1.f - zg) * n;
            if (out_f32)
                out_f32[((size_t)bi * CH + c) * HW + y * WW + x] = h;
            else
                out_f16[((size_t)bi * HW + y * WW + x) * 64 + c] = (_Float16)h;
        }
    }
}

// ---------------------------------------------------------------------------
extern "C" void kernel_launch(void* const* d_in, const int* in_sizes, int n_in,
                              void* d_out, int out_size, void* d_ws, size_t ws_size,
                              hipStream_t stream) {
    const float* feats = (const float*)d_in[0];
    const float* trans = (const float*)d_in[1];
    const float* wx    = (const float*)d_in[2];
    // d_in[3] = wh (unused: h0 = 0)
    const float* bx    = (const float*)d_in[4];
    const float* bh    = (const float*)d_in[5];
    float* out = (float*)d_out;

    char* ws = (char*)d_ws;
    half8*    wpack = (half8*)ws;                              // 442,368 B
    _Float16* B1 = (_Float16*)(ws + 442368);                   // 21 MB NHWC-64 f16
    _Float16* B2 = (_Float16*)(ws + 442368 + (size_t)NIMG * HW * 64 * 2);

    pack_w_kernel<<<108, 256, 0, stream>>>(wx, wpack);
    to_nhwc_kernel<<<dim3(512, NIMG), 256, 0, stream>>>(feats, B1);

    dim3 fgrid(128, 1, NIMG);      // 16x8 px tiles, 512 threads

    // iteration 1
    fused_warp_conv<<<fgrid, 512, 0, stream>>>(B1, trans, wpack, bx, bh, nullptr, B2);
    // iteration 2
    fused_warp_conv<<<fgrid, 512, 0, stream>>>(B2, trans, wpack, bx, bh, out, nullptr);
}

// Round 6
// 293.394 us; speedup vs baseline: 1.1710x; 1.0650x over previous
//
#include <hip/hip_runtime.h>
#include <cmath>

#define BB 2
#define AA 5
#define CH 64
#define HH 128
#define WW 128
#define HW (HH*WW)
#define NIMG (BB*AA)

typedef __attribute__((ext_vector_type(8))) _Float16 half8;
typedef __attribute__((ext_vector_type(4))) float floatx4;
typedef unsigned int uint32;

__device__ inline half8 hzero() {
    half8 v;
#pragma unroll
    for (int e = 0; e < 8; ++e) v[e] = (_Float16)0.f;
    return v;
}

__device__ inline float fsigmoid(float x) {
    return __builtin_amdgcn_rcpf(1.f + __builtin_amdgcn_exp2f(-1.442695041f * x));
}
__device__ inline float ftanh(float x) {
    return 2.f * fsigmoid(2.f * x) - 1.f;
}

// ---------------------------------------------------------------------------
// prep: fused to_nhwc + pack_w (one launch instead of two).
// blocks 0..5119: feats fp32 planar [NIMG,64,H,W] -> NHWC f16 [NIMG,HW,64]
// blocks 5120..5227: wx [192,128,3,3] fp32 -> f16 B-fragment layout
// ---------------------------------------------------------------------------
__global__ __launch_bounds__(256) void prep_kernel(
    const float* __restrict__ feats, const float* __restrict__ wx,
    _Float16* __restrict__ dst, half8* __restrict__ wp)
{
    const int bid = blockIdx.x;
    if (bid < 5120) {
        const int img = bid >> 9;
        const int inner = bid & 511;
        const int cg  = inner & 7;
        const int pb  = inner >> 3;
        const int p   = pb * 256 + threadIdx.x;
        const float* s = feats + ((size_t)img * CH + cg * 8) * HW + p;
        half8 v;
#pragma unroll
        for (int e = 0; e < 8; ++e) v[e] = (_Float16)s[e * HW];
        *(half8*)(dst + ((size_t)img * HW + p) * 64 + cg * 8) = v;
    } else {
        int idx = (bid - 5120) * 256 + threadIdx.x;   // 4*9*4*192 = 27648
        if (idx >= 4 * 9 * 4 * 192) return;
        int oc = idx % 192; int r = idx / 192;
        int gk = r & 3; r >>= 2; int tap = r % 9; int cc = r / 9;
        int ky = tap / 3, kx = tap % 3;
        half8 v;
#pragma unroll
        for (int e = 0; e < 8; ++e)
            v[e] = (_Float16)wx[(((size_t)oc * 128 + cc * 32 + gk * 8 + e) * 3 + ky) * 3 + kx];
        wp[idx] = v;
    }
}

// ---------------------------------------------------------------------------
// v13: fused warp_mean + conv + GRU (v12 structure) with a VALU-thinned
// gather. v12 counters: VALU-busy 55 µs (largest pipe), MFMA-busy 32 µs,
// dur 114.3. The gather inner loop spent ~72 VALU/pt on cvt-heavy f32
// blending. Now: (a) corner blend in packed f16 (v_pk_fma_f16: 16 packed
// ops replace 32 f32 FMA + 40 cvt); (b) affine addressing reduced to
// 2 FMA/coord via per-j constant (algebraically identical).
// ---------------------------------------------------------------------------
#define APL2 180   // g-plane stride in half8 units (10*18)

__global__ __launch_bounds__(512, 4) void fused_warp_conv(
    const _Float16* __restrict__ in,    // [NIMG, HW, 64] prev feats (f16)
    const float* __restrict__ trans,    // [B, A, A, 4, 4]
    const half8* __restrict__ wp,       // packed weights [36][768]
    const float* __restrict__ bx,       // [192]
    const float* __restrict__ bh,       // [192]
    float* __restrict__ out_f32,        // [NIMG,64,H,W] or null
    _Float16* __restrict__ out_f16)     // [NIMG,HW,64] or null
{
    __shared__ half8 lds_in[16 * APL2];   // 46080 B: 16 ch-octet planes x 10x18
    __shared__ half8 f_lds[209 * 8];      // 26752 B: 19x11 gather pts x 8 octets

    const int tid = threadIdx.x;
    const int bi  = blockIdx.z;
    const int b   = bi / AA, i = bi % AA;
    const int x0 = (blockIdx.x & 7) * 16;       // 8 x-tiles
    const int y0 = (blockIdx.x >> 3) * 8;       // 16 y-tiles

    // conv roles
    const int w   = tid >> 6;                   // wave 0..7
    const int wo  = w & 3;                      // oc-group
    const int wh  = w >> 2;                     // y-half
    const int ln  = tid & 15;
    const int kq  = (tid & 63) >> 4;
    // gather roles
    const int slc = tid & 7;                    // ch octet
    const int ptb = tid >> 3;                   // 0..63 point slot

    // ---- phase 0: direct halo ch0..63 -> planes 0..7 ----
    const _Float16* inimg = in + (size_t)bi * HW * 64;
    for (int f = tid; f < 1440; f += 512) {
        const int g = f / 180; const int r = f % 180;
        const int row = r / 18; const int col = r % 18;
        const int y = y0 + row - 1, x = x0 + col - 1;
        half8 v = hzero();
        if ((unsigned)x < (unsigned)WW && (unsigned)y < (unsigned)HH)
            v = *(const half8*)(inimg + ((size_t)y * WW + x) * 64 + g * 8);
        lds_in[g * APL2 + r] = v;
    }

    // ---- phase 1: warp-mean over j != i for the 18x10 halo ----
    half8 macc[3];
#pragma unroll
    for (int k2 = 0; k2 < 3; ++k2) macc[k2] = hzero();

    for (int j = 0; j < AA; ++j) {
        if (j == i) continue;
        const float* t = trans + (((size_t)b * AA + i) * AA + j) * 16;
        const float t00 = t[0], t01 = t[1], t03 = t[3];
        const float t10 = t[4], t11 = t[5], t13 = t[7];
        const float dxs = 2.f * t03;
        const float dys = -2.f * t13;
        const float sxf = floorf(dxs), syf = floorf(dys);
        const int sx = (int)sxf, sy = (int)syf;
        const float fx = dxs - sxf, fy = dys - syf;
        // px = 64*(t00*xn + t01*yn) + 63.5 with xn=(2qx+1)/128-1
        //    = t00*qx + t01*qy + Cx   (exact algebra)
        const float Cx = (0.5f - 64.f) * (t00 + t01) + 63.5f;
        const float Cy = (0.5f - 64.f) * (t10 + t11) + 63.5f;
        const _Float16* srcj = in + (size_t)(b * AA + j) * HW * 64 + slc * 8;

        __syncthreads();   // f_lds free of previous j's readers
#pragma unroll
        for (int it = 0; it < 4; ++it) {
            const int pt = it * 64 + ptb;
            if (pt < 209) {
                const int prow = pt / 19;
                const int pcol = pt - prow * 19;
                const int qx = x0 - 1 + sx + pcol;
                const int qy = y0 - 1 + sy + prow;
                half8 ev = hzero();
                if (((unsigned)qx < (unsigned)WW) & ((unsigned)qy < (unsigned)HH)) {
                    const float px = t00 * (float)qx + t01 * (float)qy + Cx;
                    const float py = t10 * (float)qx + t11 * (float)qy + Cy;
                    const float x0f = floorf(px), y0f = floorf(py);
                    const int ix0 = (int)x0f, iy0 = (int)y0f;
                    const float wx1 = px - x0f, wx0 = 1.f - wx1;
                    const float wy1 = py - y0f, wy0 = 1.f - wy1;
                    const bool vx0 = (ix0 >= 0) & (ix0 < WW);
                    const bool vx1 = (ix0 + 1 >= 0) & (ix0 + 1 < WW);
                    const bool vy0 = (iy0 >= 0) & (iy0 < HH);
                    const bool vy1 = (iy0 + 1 >= 0) & (iy0 + 1 < HH);
                    const int cx0 = min(max(ix0, 0), WW - 1);
                    const int cx1 = min(max(ix0 + 1, 0), WW - 1);
                    const int cy0 = min(max(iy0, 0), HH - 1);
                    const int cy1 = min(max(iy0 + 1, 0), HH - 1);
                    const float w00 = (vx0 & vy0) ? wx0 * wy0 : 0.f;
                    const float w01 = (vx1 & vy0) ? wx1 * wy0 : 0.f;
                    const float w10 = (vx0 & vy1) ? wx0 * wy1 : 0.f;
                    const float w11 = (vx1 & vy1) ? wx1 * wy1 : 0.f;
                    const half8 A  = *(const half8*)(srcj + ((size_t)cy0 * WW + cx0) * 64);
                    const half8 Bv = *(const half8*)(srcj + ((size_t)cy0 * WW + cx1) * 64);
                    const half8 Cv = *(const half8*)(srcj + ((size_t)cy1 * WW + cx0) * 64);
                    const half8 D  = *(const half8*)(srcj + ((size_t)cy1 * WW + cx1) * 64);
                    // packed f16 blend: 16 v_pk_fma_f16, no cvt chain
                    ev = A  * (half8)(_Float16)w00 + Bv * (half8)(_Float16)w01
                       + Cv * (half8)(_Float16)w10 + D  * (half8)(_Float16)w11;
                }
                f_lds[pt * 8 + slc] = ev;
            }
        }
        __syncthreads();   // staging visible

        const half8 wA8 = (half8)(_Float16)((1.f - fx) * (1.f - fy));
        const half8 wB8 = (half8)(_Float16)(fx * (1.f - fy));
        const half8 wC8 = (half8)(_Float16)((1.f - fx) * fy);
        const half8 wD8 = (half8)(_Float16)(fx * fy);
#pragma unroll
        for (int k2 = 0; k2 < 3; ++k2) {
            const int item = tid + 512 * k2;
            if (item < 1440) {
                const int px = item >> 3, g = item & 7;
                const int row = px / 18, col = px - row * 18;
                const half8* fp = &f_lds[(row * 19 + col) * 8 + g];
                macc[k2] += fp[0] * wA8 + fp[8] * wB8 + fp[152] * wC8 + fp[160] * wD8;
            }
        }
    }

    // mean -> planes 8..15 (zero outside image, matching old bounds check)
    {
        const half8 q8 = (half8)(_Float16)0.25f;   // 1/(A-1)
#pragma unroll
        for (int k2 = 0; k2 < 3; ++k2) {
            const int item = tid + 512 * k2;
            if (item < 1440) {
                const int px = item >> 3, g = item & 7;
                const int row = px / 18, col = px - row * 18;
                const int y = y0 + row - 1, x = x0 + col - 1;
                half8 v = hzero();
                if ((unsigned)x < (unsigned)WW && (unsigned)y < (unsigned)HH)
                    v = macc[k2] * q8;
                lds_in[(8 + g) * APL2 + row * 18 + col] = v;
            }
        }
    }

    floatx4 acc[4][3];     // [y-row][gate]
#pragma unroll
    for (int s = 0; s < 4; ++s)
#pragma unroll
        for (int t = 0; t < 3; ++t)
#pragma unroll
            for (int r = 0; r < 4; ++r) acc[s][t][r] = 0.f;

    __syncthreads();

    // ---- phase 2: verified barrier-free K-loop, depth-2 b prefetch ----
    const half8* wbase = wp + kq * 192 + wo * 16 + ln;
    half8 bp0[3], bp1[3];
#pragma unroll
    for (int t = 0; t < 3; ++t) bp0[t] = wbase[t * 64];
#pragma unroll
    for (int t = 0; t < 3; ++t) bp1[t] = wbase[768 + t * 64];

#pragma unroll
    for (int s = 0; s < 36; ++s) {
        const int cc = s / 9, tap = s - cc * 9;
        const int dy = tap / 3, dx = tap - dy * 3;
        half8 bcur[3];
#pragma unroll
        for (int t = 0; t < 3; ++t) { bcur[t] = bp0[t]; bp0[t] = bp1[t]; }
        if (s + 2 < 36) {
            const half8* wsrc = wbase + (size_t)(s + 2) * 768;
#pragma unroll
            for (int t = 0; t < 3; ++t) bp1[t] = wsrc[t * 64];
        }
        half8 a[4];
#pragma unroll
        for (int t = 0; t < 4; ++t)
            a[t] = lds_in[(cc * 4 + kq) * APL2 + (wh * 4 + t + dy) * 18 + ln + dx];
#pragma unroll
        for (int t = 0; t < 4; ++t)
#pragma unroll
            for (int u = 0; u < 3; ++u)
                acc[t][u] = __builtin_amdgcn_mfma_f32_16x16x32_f16(a[t], bcur[u], acc[t][u], 0, 0, 0);
    }

    // epilogue: GRU gating. D layout: col(oc%16)=ln, row(x)=kq*4+reg.
    const int c = wo * 16 + ln;                 // 0..63
    const float bxr = bx[c] + bh[c];
    const float bxz = bx[64 + c] + bh[64 + c];
    const float bxn = bx[128 + c];
    const float bnn = bh[128 + c];
#pragma unroll
    for (int s = 0; s < 4; ++s) {
        const int y = y0 + wh * 4 + s;
#pragma unroll
        for (int reg = 0; reg < 4; ++reg) {
            const int x = x0 + kq * 4 + reg;
            const float xr = acc[s][0][reg] + bxr;
            const float xz = acc[s][1][reg] + bxz;
            const float xn = acc[s][2][reg] + bxn;
            const float rg = fsigmoid(xr);
            const float zg = fsigmoid(xz);
            const float n  = ftanh(xn + rg * bnn);
            const float h  = (1.f - zg) * n;
            if (out_f32)
                out_f32[((size_t)bi * CH + c) * HW + y * WW + x] = h;
            else
                out_f16[((size_t)bi * HW + y * WW + x) * 64 + c] = (_Float16)h;
        }
    }
}

// ---------------------------------------------------------------------------
extern "C" void kernel_launch(void* const* d_in, const int* in_sizes, int n_in,
                              void* d_out, int out_size, void* d_ws, size_t ws_size,
                              hipStream_t stream) {
    const float* feats = (const float*)d_in[0];
    const float* trans = (const float*)d_in[1];
    const float* wx    = (const float*)d_in[2];
    // d_in[3] = wh (unused: h0 = 0)
    const float* bx    = (const float*)d_in[4];
    const float* bh    = (const float*)d_in[5];
    float* out = (float*)d_out;

    char* ws = (char*)d_ws;
    half8*    wpack = (half8*)ws;                              // 442,368 B
    _Float16* B1 = (_Float16*)(ws + 442368);                   // 21 MB NHWC-64 f16
    _Float16* B2 = (_Float16*)(ws + 442368 + (size_t)NIMG * HW * 64 * 2);

    prep_kernel<<<5228, 256, 0, stream>>>(feats, wx, B1, wpack);

    dim3 fgrid(128, 1, NIMG);      // 16x8 px tiles, 512 threads

    // iteration 1
    fused_warp_conv<<<fgrid, 512, 0, stream>>>(B1, trans, wpack, bx, bh, nullptr, B2);
    // iteration 2
    fused_warp_conv<<<fgrid, 512, 0, stream>>>(B2, trans, wpack, bx, bh, out, nullptr);
}